// Round 1
// baseline (768.196 us; speedup 1.0000x reference)
//
#include <hip/hip_runtime.h>
#include <math.h>

#define NB 4096
#define KN 64
#define DIM 128
#define PITCH 132   // 132 floats = 528B, 16B-aligned rows, bank-conflict-free (2-way max)

__global__ __launch_bounds__(256, 2) void graphsage_fused(
    const int* __restrict__ node_idx,
    const int* __restrict__ neigh_idx,
    const int* __restrict__ neigh_len,
    const float* __restrict__ emb_v,
    const float* __restrict__ emb_t,
    const float* __restrict__ w1,
    const float* __restrict__ b1,
    const float* __restrict__ w2,
    const float* __restrict__ b2,
    const float* __restrict__ w3,
    float* __restrict__ out)
{
    __shared__ float n_lds[KN][PITCH];
    __shared__ float h1_lds[KN][PITCH];
    __shared__ float u_lds[DIM];
    __shared__ float uq[DIM];
    __shared__ float part[2][DIM];
    __shared__ float s_lds[KN];
    __shared__ float att_lds[KN];
    __shared__ int   ni_lds[KN];

    const int b   = blockIdx.x;
    const int tid = threadIdx.x;
    const int nd  = node_idx[b];
    const int len = neigh_len[b];

    if (tid < KN) ni_lds[tid] = neigh_idx[b * KN + tid];
    __syncthreads();

    const int kq = tid >> 4;   // 0..15 -> k group of 4
    const int jq = tid & 15;   // 0..15 -> j group of 8
    const int k0 = kq * 4;
    const int j0 = jq * 8;

    for (int m = 0; m < 2; ++m) {
        const float* __restrict__ emb = m ? emb_t : emb_v;

        // ---- load u (self features), write passthrough output ----
        if (tid < DIM) {
            float uv = emb[(long)nd * DIM + tid];
            u_lds[tid] = uv;
            out[((long)m * NB + b) * DIM + tid] = uv;
        }

        if (len == 0) {
            // empty neighbor list -> aggregated output is the self rep
            if (tid < DIM) {
                out[((long)(2 + m) * NB + b) * DIM + tid] = u_lds[tid];
            }
            __syncthreads();
            continue;
        }

        // ---- gather valid neighbor rows into LDS (float4 coalesced) ----
        for (int t = tid; t < KN * 32; t += 256) {
            int r = t >> 5;
            int c = t & 31;
            if (r < len) {
                float4 v = ((const float4*)(emb + (long)ni_lds[r] * DIM))[c];
                ((float4*)&n_lds[r][0])[c] = v;
            }
        }
        __syncthreads();

        // ---- uq[j] = sum_i u[i]*w1[128+i][j] + b1[j]  (node half of layer 1) ----
        {
            int half = tid >> 7;
            int j = tid & 127;
            float acc = 0.f;
            for (int i = 0; i < 64; ++i) {
                int ii = half * 64 + i;
                acc = fmaf(u_lds[ii], w1[(128 + ii) * DIM + j], acc);
            }
            part[half][j] = acc;
        }
        __syncthreads();
        if (tid < DIM) uq[tid] = part[0][tid] + part[1][tid] + b1[tid];
        __syncthreads();

        // ---- GEMM1: h1[k][j] = relu(sum_i n[k][i]*w1[i][j] + uq[j]) ----
        if (k0 < len) {
            float acc[4][8];
            #pragma unroll
            for (int d = 0; d < 4; ++d)
                #pragma unroll
                for (int u = 0; u < 8; ++u)
                    acc[d][u] = uq[j0 + u];
            for (int i = 0; i < DIM; ++i) {
                float4 wa = *(const float4*)(w1 + i * DIM + j0);
                float4 wb = *(const float4*)(w1 + i * DIM + j0 + 4);
                float w[8] = {wa.x, wa.y, wa.z, wa.w, wb.x, wb.y, wb.z, wb.w};
                #pragma unroll
                for (int d = 0; d < 4; ++d) {
                    float nv = n_lds[k0 + d][i];
                    #pragma unroll
                    for (int u = 0; u < 8; ++u)
                        acc[d][u] = fmaf(nv, w[u], acc[d][u]);
                }
            }
            #pragma unroll
            for (int d = 0; d < 4; ++d)
                #pragma unroll
                for (int u = 0; u < 8; ++u)
                    h1_lds[k0 + d][j0 + u] = fmaxf(acc[d][u], 0.f);
        }
        __syncthreads();

        // ---- GEMM2 + relu + score: s[k] = sum_j relu(h1@w2+b2)[k][j]*w3[j] ----
        if (k0 < len) {
            float acc2[4][8];
            float b2v[8], w3v[8];
            #pragma unroll
            for (int u = 0; u < 8; ++u) {
                b2v[u] = b2[j0 + u];
                w3v[u] = w3[j0 + u];
            }
            #pragma unroll
            for (int d = 0; d < 4; ++d)
                #pragma unroll
                for (int u = 0; u < 8; ++u)
                    acc2[d][u] = b2v[u];
            for (int i = 0; i < DIM; ++i) {
                float4 wa = *(const float4*)(w2 + i * DIM + j0);
                float4 wb = *(const float4*)(w2 + i * DIM + j0 + 4);
                float w[8] = {wa.x, wa.y, wa.z, wa.w, wb.x, wb.y, wb.z, wb.w};
                #pragma unroll
                for (int d = 0; d < 4; ++d) {
                    float hv = h1_lds[k0 + d][i];
                    #pragma unroll
                    for (int u = 0; u < 8; ++u)
                        acc2[d][u] = fmaf(hv, w[u], acc2[d][u]);
                }
            }
            float p[4];
            #pragma unroll
            for (int d = 0; d < 4; ++d) {
                float s = 0.f;
                #pragma unroll
                for (int u = 0; u < 8; ++u)
                    s = fmaf(fmaxf(acc2[d][u], 0.f), w3v[u], s);
                p[d] = s;
            }
            // reduce across the 16 jq lanes (uniform guard within 16-lane group)
            #pragma unroll
            for (int off = 1; off < 16; off <<= 1) {
                #pragma unroll
                for (int d = 0; d < 4; ++d)
                    p[d] += __shfl_xor(p[d], off);
            }
            if (jq == 0) {
                #pragma unroll
                for (int d = 0; d < 4; ++d)
                    s_lds[k0 + d] = p[d];
            }
        }
        __syncthreads();

        // ---- masked softmax over k (wave 0 only) ----
        if (tid < KN) {
            int k = tid;
            float sv = (k < len) ? s_lds[k] : -INFINITY;
            float mx = sv;
            #pragma unroll
            for (int off = 1; off < 64; off <<= 1)
                mx = fmaxf(mx, __shfl_xor(mx, off));
            float e = (k < len) ? __expf(sv - mx) : 0.f;
            float sum = e;
            #pragma unroll
            for (int off = 1; off < 64; off <<= 1)
                sum += __shfl_xor(sum, off);
            att_lds[k] = e / sum;
        }
        __syncthreads();

        // ---- aggregate: agg[j] = sum_{k<len} att[k]*n[k][j] ----
        {
            int half = tid >> 7;
            int j = tid & 127;
            float ag = 0.f;
            int kbeg = half * 32;
            int kend = min(len, kbeg + 32);
            for (int k = kbeg; k < kend; ++k)
                ag = fmaf(att_lds[k], n_lds[k][j], ag);
            part[half][j] = ag;
        }
        __syncthreads();
        if (tid < DIM)
            out[((long)(2 + m) * NB + b) * DIM + tid] = part[0][tid] + part[1][tid];
        __syncthreads();  // before LDS reuse by next modality
    }
}

extern "C" void kernel_launch(void* const* d_in, const int* in_sizes, int n_in,
                              void* d_out, int out_size, void* d_ws, size_t ws_size,
                              hipStream_t stream) {
    const int*   node_idx  = (const int*)d_in[0];
    const int*   neigh_idx = (const int*)d_in[1];
    const int*   neigh_len = (const int*)d_in[2];
    const float* emb_v     = (const float*)d_in[3];
    const float* emb_t     = (const float*)d_in[4];
    const float* w1        = (const float*)d_in[5];
    const float* b1        = (const float*)d_in[6];
    const float* w2        = (const float*)d_in[7];
    const float* b2        = (const float*)d_in[8];
    const float* w3        = (const float*)d_in[9];
    float* out = (float*)d_out;

    hipLaunchKernelGGL(graphsage_fused, dim3(NB), dim3(256), 0, stream,
                       node_idx, neigh_idx, neigh_len,
                       emb_v, emb_t, w1, b1, w2, b2, w3, out);
}

// Round 2
// 139.621 us; speedup vs baseline: 5.5020x; 5.5020x over previous
//
#include <hip/hip_runtime.h>
#include <math.h>

#define NB 4096
#define KN 64
#define DIM 128
#define HP 136   // LDS pitch in bf16: 272B/row = 16B-aligned, 4-bank rotation per row

typedef __bf16 bf16;
typedef bf16 bf16x8 __attribute__((ext_vector_type(8)));
typedef float f32x4 __attribute__((ext_vector_type(4)));

// ---- prep: transpose+convert weights to bf16 in d_ws ----
// w1T[j][i] = w1[i][j], j in [0,128), i in [0,256)   (row-major, 256 wide)
// w2T[j2][j1] = w2[j1][j2], both in [0,128)
__global__ void prep_weights(const float* __restrict__ w1,
                             const float* __restrict__ w2,
                             bf16* __restrict__ w1T,
                             bf16* __restrict__ w2T) {
    int t = blockIdx.x * 256 + threadIdx.x;
    if (t < 128 * 256) {
        int j = t >> 8, i = t & 255;
        w1T[t] = (bf16)w1[i * 128 + j];
    } else {
        int t2 = t - 128 * 256;
        int j2 = t2 >> 7, j1 = t2 & 127;
        w2T[t2] = (bf16)w2[j1 * 128 + j2];
    }
}

__global__ __launch_bounds__(256, 4) void graphsage_mfma(
    const int* __restrict__ node_idx,
    const int* __restrict__ neigh_idx,
    const int* __restrict__ neigh_len,
    const float* __restrict__ emb_v,
    const float* __restrict__ emb_t,
    const bf16* __restrict__ w1T,
    const float* __restrict__ b1,
    const bf16* __restrict__ w2T,
    const float* __restrict__ b2,
    const float* __restrict__ w3,
    float* __restrict__ out)
{
    __shared__ bf16 n_lds[KN][HP];     // gathered neighbors (bf16), zero-filled invalid
    __shared__ bf16 h1_lds[KN][HP];    // GEMM1 output
    __shared__ float u_lds[DIM];
    __shared__ float uq_lds[DIM];
    __shared__ float s_part[4][KN];    // per-wave score partials
    __shared__ float att_lds[KN];
    __shared__ float part2[2][DIM];    // uq partials / agg partials

    const int b   = blockIdx.x;
    const int tid = threadIdx.x;
    const int nd  = node_idx[b];
    const int len = neigh_len[b];

    const int wv = tid >> 6;          // wave 0..3
    const int ll = tid & 15;          // lane&15
    const int lh = (tid >> 4) & 3;    // lane>>4 within wave

    for (int m = 0; m < 2; ++m) {
        const float* __restrict__ emb = m ? emb_t : emb_v;

        // ---- self features: passthrough output (+ fallback when no neighbors) ----
        if (tid < DIM) {
            float uv = emb[(size_t)nd * DIM + tid];
            u_lds[tid] = uv;
            out[((size_t)m * NB + b) * DIM + tid] = uv;
            if (len == 0)
                out[((size_t)(2 + m) * NB + b) * DIM + tid] = uv;
        }
        if (len == 0) { __syncthreads(); continue; }  // uniform per block

        // ---- gather neighbor rows -> bf16 LDS; zero-fill rows >= len ----
        #pragma unroll
        for (int it = 0; it < 4; ++it) {
            int c = tid + it * 256;          // 1024 chunks of 8 cols
            int r = c >> 4, c8 = c & 15;
            bf16x8 v;
            if (r < len) {
                const float* src = emb + (size_t)neigh_idx[b * KN + r] * DIM + c8 * 8;
                float4 f0 = ((const float4*)src)[0];
                float4 f1 = ((const float4*)src)[1];
                v[0] = (bf16)f0.x; v[1] = (bf16)f0.y; v[2] = (bf16)f0.z; v[3] = (bf16)f0.w;
                v[4] = (bf16)f1.x; v[5] = (bf16)f1.y; v[6] = (bf16)f1.z; v[7] = (bf16)f1.w;
            } else {
                #pragma unroll
                for (int q = 0; q < 8; ++q) v[q] = (bf16)0.f;
            }
            *(bf16x8*)&n_lds[r][c8 * 8] = v;
        }
        __syncthreads();  // n_lds + u_lds ready

        // ---- uq[j] = u @ W1bot[:,j] + b1[j]  (node half of layer-1) ----
        {
            int j = tid & 127, h = tid >> 7;
            const bf16* wb = w1T + (size_t)j * 256 + DIM + h * 64;
            const float* us = &u_lds[h * 64];
            float a = 0.f;
            #pragma unroll
            for (int i = 0; i < 64; i += 8) {
                bf16x8 wvv = *(const bf16x8*)(wb + i);
                #pragma unroll
                for (int q = 0; q < 8; ++q) a = fmaf(us[i + q], (float)wvv[q], a);
            }
            part2[h][j] = a;
        }
        __syncthreads();
        if (tid < DIM) uq_lds[tid] = part2[0][tid] + part2[1][tid] + b1[tid];
        __syncthreads();

        // ---- GEMM1 (MFMA): H1 = relu(N @ W1top + uq) ----
        // wave wv owns j1 in [32*wv, 32*wv+32); M-tiles mt = neighbor groups
        {
            bf16x8 bfrag[2][4];
            #pragma unroll
            for (int nt = 0; nt < 2; ++nt)
                #pragma unroll
                for (int ks = 0; ks < 4; ++ks)
                    bfrag[nt][ks] = *(const bf16x8*)(w1T + (size_t)(wv * 32 + nt * 16 + ll) * 256 + ks * 32 + lh * 8);

            f32x4 zero4 = {0.f, 0.f, 0.f, 0.f};
            f32x4 acc[4][2];
            #pragma unroll
            for (int mt = 0; mt < 4; ++mt) { acc[mt][0] = zero4; acc[mt][1] = zero4; }

            #pragma unroll
            for (int mt = 0; mt < 4; ++mt)
                #pragma unroll
                for (int ks = 0; ks < 4; ++ks) {
                    bf16x8 a = *(const bf16x8*)&n_lds[mt * 16 + ll][ks * 32 + lh * 8];
                    acc[mt][0] = __builtin_amdgcn_mfma_f32_16x16x32_bf16(a, bfrag[0][ks], acc[mt][0], 0, 0, 0);
                    acc[mt][1] = __builtin_amdgcn_mfma_f32_16x16x32_bf16(a, bfrag[1][ks], acc[mt][1], 0, 0, 0);
                }

            // epilogue: +uq, relu, store bf16 (acc: col j1 = l&15, row kk = 4*lh+r)
            #pragma unroll
            for (int nt = 0; nt < 2; ++nt) {
                float uqv = uq_lds[wv * 32 + nt * 16 + ll];
                #pragma unroll
                for (int mt = 0; mt < 4; ++mt)
                    #pragma unroll
                    for (int r = 0; r < 4; ++r) {
                        float h = acc[mt][nt][r] + uqv;
                        h1_lds[mt * 16 + lh * 4 + r][wv * 32 + nt * 16 + ll] = (bf16)fmaxf(h, 0.f);
                    }
            }
        }
        __syncthreads();

        // ---- GEMM2 (MFMA, swapped): H2^T = W2^T @ H1^T, fused bias+relu+score ----
        // wave wv owns j2 in [32*wv, 32*wv+32); N-tiles ntk = neighbor groups
        {
            bf16x8 afrag[2][4];
            #pragma unroll
            for (int mtl = 0; mtl < 2; ++mtl)
                #pragma unroll
                for (int ks = 0; ks < 4; ++ks)
                    afrag[mtl][ks] = *(const bf16x8*)(w2T + (size_t)(wv * 32 + mtl * 16 + ll) * 128 + ks * 32 + lh * 8);

            f32x4 zero4 = {0.f, 0.f, 0.f, 0.f};
            f32x4 acc2[2][4];
            #pragma unroll
            for (int ntk = 0; ntk < 4; ++ntk) { acc2[0][ntk] = zero4; acc2[1][ntk] = zero4; }

            #pragma unroll
            for (int ntk = 0; ntk < 4; ++ntk)
                #pragma unroll
                for (int ks = 0; ks < 4; ++ks) {
                    bf16x8 bf = *(const bf16x8*)&h1_lds[ntk * 16 + ll][ks * 32 + lh * 8];
                    acc2[0][ntk] = __builtin_amdgcn_mfma_f32_16x16x32_bf16(afrag[0][ks], bf, acc2[0][ntk], 0, 0, 0);
                    acc2[1][ntk] = __builtin_amdgcn_mfma_f32_16x16x32_bf16(afrag[1][ks], bf, acc2[1][ntk], 0, 0, 0);
                }

            // score: s[kk] = sum_j2 relu(H2[kk][j2]+b2[j2]) * w3[j2]
            // acc2: col kk = ntk*16 + ll, row j2 = wv*32 + mtl*16 + lh*4 + r
            float4 w3a = *(const float4*)(w3 + wv * 32 + lh * 4);
            float4 w3b = *(const float4*)(w3 + wv * 32 + 16 + lh * 4);
            float4 b2a = *(const float4*)(b2 + wv * 32 + lh * 4);
            float4 b2b = *(const float4*)(b2 + wv * 32 + 16 + lh * 4);
            float w3arr[8] = {w3a.x, w3a.y, w3a.z, w3a.w, w3b.x, w3b.y, w3b.z, w3b.w};
            float b2arr[8] = {b2a.x, b2a.y, b2a.z, b2a.w, b2b.x, b2b.y, b2b.z, b2b.w};
            #pragma unroll
            for (int ntk = 0; ntk < 4; ++ntk) {
                float s = 0.f;
                #pragma unroll
                for (int r = 0; r < 4; ++r) {
                    s = fmaf(fmaxf(acc2[0][ntk][r] + b2arr[r],     0.f), w3arr[r],     s);
                    s = fmaf(fmaxf(acc2[1][ntk][r] + b2arr[4 + r], 0.f), w3arr[4 + r], s);
                }
                s += __shfl_xor(s, 16);
                s += __shfl_xor(s, 32);
                if (lh == 0) s_part[wv][ntk * 16 + ll] = s;
            }
        }
        __syncthreads();

        // ---- masked softmax over neighbors (wave 0) ----
        if (tid < KN) {
            float s = s_part[0][tid] + s_part[1][tid] + s_part[2][tid] + s_part[3][tid];
            float sv = (tid < len) ? s : -INFINITY;
            float mx = sv;
            #pragma unroll
            for (int off = 1; off < 64; off <<= 1) mx = fmaxf(mx, __shfl_xor(mx, off));
            float e = (tid < len) ? __expf(sv - mx) : 0.f;
            float sum = e;
            #pragma unroll
            for (int off = 1; off < 64; off <<= 1) sum += __shfl_xor(sum, off);
            att_lds[tid] = e / sum;
        }
        __syncthreads();

        // ---- aggregate: agg[j] = sum_{k<len} att[k] * N[k][j] ----
        {
            int j = tid & 127, h = tid >> 7;
            float ag = 0.f;
            int ke = min(len, h * 32 + 32);
            for (int k = h * 32; k < ke; ++k)
                ag = fmaf(att_lds[k], (float)n_lds[k][j], ag);
            part2[h][j] = ag;
        }
        __syncthreads();
        if (tid < DIM)
            out[((size_t)(2 + m) * NB + b) * DIM + tid] = part2[0][tid] + part2[1][tid];
        __syncthreads();  // protect LDS before next modality overwrites
    }
}

extern "C" void kernel_launch(void* const* d_in, const int* in_sizes, int n_in,
                              void* d_out, int out_size, void* d_ws, size_t ws_size,
                              hipStream_t stream) {
    const int*   node_idx  = (const int*)d_in[0];
    const int*   neigh_idx = (const int*)d_in[1];
    const int*   neigh_len = (const int*)d_in[2];
    const float* emb_v     = (const float*)d_in[3];
    const float* emb_t     = (const float*)d_in[4];
    const float* w1        = (const float*)d_in[5];
    const float* b1        = (const float*)d_in[6];
    const float* w2        = (const float*)d_in[7];
    const float* b2        = (const float*)d_in[8];
    const float* w3        = (const float*)d_in[9];
    float* out = (float*)d_out;

    bf16* w1T = (bf16*)d_ws;                 // 128*256 bf16 = 64 KiB
    bf16* w2T = (bf16*)d_ws + 128 * 256;     // 128*128 bf16 = 32 KiB

    hipLaunchKernelGGL(prep_weights, dim3(192), dim3(256), 0, stream, w1, w2, w1T, w2T);
    hipLaunchKernelGGL(graphsage_mfma, dim3(NB), dim3(256), 0, stream,
                       node_idx, neigh_idx, neigh_len, emb_v, emb_t,
                       w1T, b1, w2T, b2, w3, out);
}

// Round 3
// 96.729 us; speedup vs baseline: 7.9418x; 1.4434x over previous
//
#include <hip/hip_runtime.h>
#include <math.h>

#define NB 4096
#define KN 64
#define DIM 128
#define HP 136   // LDS pitch in bf16: 272B/row, 16B-aligned, conflict-benign for b128 frags

typedef __bf16 bf16;
typedef bf16 bf16x8 __attribute__((ext_vector_type(8)));
typedef bf16 bf16x4 __attribute__((ext_vector_type(4)));
typedef float f32x4 __attribute__((ext_vector_type(4)));

// ---- prep: transpose+convert weights to bf16 in d_ws ----
// w1T[j][i] = w1[i][j], j in [0,128), i in [0,256)
// w2T[j2][j1] = w2[j1][j2]
__global__ void prep_weights(const float* __restrict__ w1,
                             const float* __restrict__ w2,
                             bf16* __restrict__ w1T,
                             bf16* __restrict__ w2T) {
    int t = blockIdx.x * 256 + threadIdx.x;
    if (t < 128 * 256) {
        int j = t >> 8, i = t & 255;
        w1T[t] = (bf16)w1[i * 128 + j];
    } else {
        int t2 = t - 128 * 256;
        int j2 = t2 >> 7, j1 = t2 & 127;
        w2T[t2] = (bf16)w2[j1 * 128 + j2];
    }
}

__global__ __launch_bounds__(256, 4) void graphsage_mfma(
    const int* __restrict__ node_idx,
    const int* __restrict__ neigh_idx,
    const int* __restrict__ neigh_len,
    const float* __restrict__ emb_v,
    const float* __restrict__ emb_t,
    const bf16* __restrict__ w1T,
    const float* __restrict__ b1,
    const bf16* __restrict__ w2T,
    const float* __restrict__ b2,
    const float* __restrict__ w3,
    float* __restrict__ out)
{
    __shared__ bf16  n_lds[KN][HP];     // 17408 B
    __shared__ bf16  h1_lds[KN][HP];    // 17408 B (stored row kk, col j1)
    __shared__ float u_lds[2][DIM];     // 1024 B
    __shared__ float uq_lds[2][DIM];    // 1024 B
    __shared__ float scratch[4][DIM];   // 2048 B: uq partials / score partials / agg partials
    __shared__ float att_lds[KN];       // 256 B
    __shared__ int   ni_lds[KN];        // 256 B
    // total ~39.4 KB -> 4 blocks/CU

    const int b   = blockIdx.x;
    const int tid = threadIdx.x;
    const int nd  = node_idx[b];
    const int len = neigh_len[b];

    const int wv = tid >> 6;          // wave 0..3
    const int ll = tid & 15;
    const int lh = (tid >> 4) & 3;

    // ---- self features (both modalities), early exit on empty list ----
    float uvv = 0.f, uvt = 0.f;
    if (tid < DIM) {
        uvv = emb_v[(size_t)nd * DIM + tid];
        uvt = emb_t[(size_t)nd * DIM + tid];
        out[((size_t)0 * NB + b) * DIM + tid] = uvv;
        out[((size_t)1 * NB + b) * DIM + tid] = uvt;
    }
    if (len == 0) {   // block-uniform
        if (tid < DIM) {
            out[((size_t)2 * NB + b) * DIM + tid] = uvv;
            out[((size_t)3 * NB + b) * DIM + tid] = uvt;
        }
        return;
    }
    if (tid < DIM) { u_lds[0][tid] = uvv; u_lds[1][tid] = uvt; }
    if (tid < KN) ni_lds[tid] = neigh_idx[b * KN + tid];
    __syncthreads();

    // ---- uq[m][j] = u_m @ W1bot[:,j] + b1[j], both modalities in one pass ----
    {
        int j = tid & 127, h = tid >> 7;
        const bf16* wb = w1T + (size_t)j * 256 + DIM + h * 64;
        const float* usv = &u_lds[0][h * 64];
        const float* ust = &u_lds[1][h * 64];
        float av = 0.f, at = 0.f;
        #pragma unroll
        for (int i = 0; i < 64; i += 8) {
            bf16x8 w = *(const bf16x8*)(wb + i);
            #pragma unroll
            for (int q = 0; q < 8; ++q) {
                float wf = (float)w[q];
                av = fmaf(usv[i + q], wf, av);
                at = fmaf(ust[i + q], wf, at);
            }
        }
        scratch[h][j] = av;
        scratch[2 + h][j] = at;
    }
    __syncthreads();
    {
        int j = tid & 127, mm = tid >> 7;
        uq_lds[mm][j] = scratch[mm * 2][j] + scratch[mm * 2 + 1][j] + b1[j];
    }
    __syncthreads();

    const int nkt = (len + 15) >> 4;   // valid 16-row k-tiles (1..4), block-uniform
    const int lim = nkt * 16;

    for (int m = 0; m < 2; ++m) {
        const float* __restrict__ emb = m ? emb_t : emb_v;

        // ---- gather valid neighbor rows -> bf16 LDS (zero-fill partial tile) ----
        for (int c = tid; c < lim * 16; c += 256) {
            int r = c >> 4, c8 = c & 15;
            bf16x8 v;
            if (r < len) {
                const float* src = emb + (size_t)ni_lds[r] * DIM + c8 * 8;
                float4 f0 = ((const float4*)src)[0];
                float4 f1 = ((const float4*)src)[1];
                v[0] = (bf16)f0.x; v[1] = (bf16)f0.y; v[2] = (bf16)f0.z; v[3] = (bf16)f0.w;
                v[4] = (bf16)f1.x; v[5] = (bf16)f1.y; v[6] = (bf16)f1.z; v[7] = (bf16)f1.w;
            } else {
                #pragma unroll
                for (int q = 0; q < 8; ++q) v[q] = (bf16)0.f;
            }
            *(bf16x8*)&n_lds[r][c8 * 8] = v;
        }
        __syncthreads();

        // ---- GEMM1 (swapped): H1^T = W1top^T @ N^T, +uq, relu, b64-packed store ----
        // acc[jt][kt]: row j1 = wv*32 + jt*16 + lh*4 + r, col kk = kt*16 + ll
        {
            bf16x8 af[2][4];
            #pragma unroll
            for (int jt = 0; jt < 2; ++jt)
                #pragma unroll
                for (int ks = 0; ks < 4; ++ks)
                    af[jt][ks] = *(const bf16x8*)(w1T + (size_t)(wv * 32 + jt * 16 + ll) * 256 + ks * 32 + lh * 8);

            f32x4 zero4 = {0.f, 0.f, 0.f, 0.f};
            f32x4 acc[2][4];
            #pragma unroll
            for (int kt = 0; kt < 4; ++kt) { acc[0][kt] = zero4; acc[1][kt] = zero4; }

            #pragma unroll
            for (int kt = 0; kt < 4; ++kt) {
                if (kt < nkt) {
                    #pragma unroll
                    for (int ks = 0; ks < 4; ++ks) {
                        bf16x8 bfr = *(const bf16x8*)&n_lds[kt * 16 + ll][ks * 32 + lh * 8];
                        acc[0][kt] = __builtin_amdgcn_mfma_f32_16x16x32_bf16(af[0][ks], bfr, acc[0][kt], 0, 0, 0);
                        acc[1][kt] = __builtin_amdgcn_mfma_f32_16x16x32_bf16(af[1][ks], bfr, acc[1][kt], 0, 0, 0);
                    }
                }
            }
            #pragma unroll
            for (int jt = 0; jt < 2; ++jt) {
                float4 uq4 = *(const float4*)&uq_lds[m][wv * 32 + jt * 16 + lh * 4];
                float uqa[4] = {uq4.x, uq4.y, uq4.z, uq4.w};
                #pragma unroll
                for (int kt = 0; kt < 4; ++kt) {
                    if (kt < nkt) {
                        bf16x4 hv;
                        #pragma unroll
                        for (int r = 0; r < 4; ++r)
                            hv[r] = (bf16)fmaxf(acc[jt][kt][r] + uqa[r], 0.f);
                        *(bf16x4*)&h1_lds[kt * 16 + ll][wv * 32 + jt * 16 + lh * 4] = hv;
                    }
                }
            }
        }
        __syncthreads();

        // ---- GEMM2 (swapped): H2^T = W2^T @ H1^T, fused bias+relu+score ----
        // acc2[mtl][ntk]: row j2 = wv*32 + mtl*16 + lh*4 + r, col kk = ntk*16 + ll
        {
            bf16x8 af2[2][4];
            #pragma unroll
            for (int mtl = 0; mtl < 2; ++mtl)
                #pragma unroll
                for (int ks = 0; ks < 4; ++ks)
                    af2[mtl][ks] = *(const bf16x8*)(w2T + (size_t)(wv * 32 + mtl * 16 + ll) * 128 + ks * 32 + lh * 8);

            f32x4 zero4 = {0.f, 0.f, 0.f, 0.f};
            f32x4 acc2[2][4];
            #pragma unroll
            for (int ntk = 0; ntk < 4; ++ntk) { acc2[0][ntk] = zero4; acc2[1][ntk] = zero4; }

            #pragma unroll
            for (int ntk = 0; ntk < 4; ++ntk) {
                if (ntk < nkt) {
                    #pragma unroll
                    for (int ks = 0; ks < 4; ++ks) {
                        bf16x8 bfr = *(const bf16x8*)&h1_lds[ntk * 16 + ll][ks * 32 + lh * 8];
                        acc2[0][ntk] = __builtin_amdgcn_mfma_f32_16x16x32_bf16(af2[0][ks], bfr, acc2[0][ntk], 0, 0, 0);
                        acc2[1][ntk] = __builtin_amdgcn_mfma_f32_16x16x32_bf16(af2[1][ks], bfr, acc2[1][ntk], 0, 0, 0);
                    }
                }
            }

            float4 w3a = *(const float4*)(w3 + wv * 32 + lh * 4);
            float4 w3b = *(const float4*)(w3 + wv * 32 + 16 + lh * 4);
            float4 b2a = *(const float4*)(b2 + wv * 32 + lh * 4);
            float4 b2b = *(const float4*)(b2 + wv * 32 + 16 + lh * 4);
            float w3arr[8] = {w3a.x, w3a.y, w3a.z, w3a.w, w3b.x, w3b.y, w3b.z, w3b.w};
            float b2arr[8] = {b2a.x, b2a.y, b2a.z, b2a.w, b2b.x, b2b.y, b2b.z, b2b.w};
            #pragma unroll
            for (int ntk = 0; ntk < 4; ++ntk) {
                if (ntk < nkt) {
                    float s = 0.f;
                    #pragma unroll
                    for (int r = 0; r < 4; ++r) {
                        s = fmaf(fmaxf(acc2[0][ntk][r] + b2arr[r],     0.f), w3arr[r],     s);
                        s = fmaf(fmaxf(acc2[1][ntk][r] + b2arr[4 + r], 0.f), w3arr[4 + r], s);
                    }
                    s += __shfl_xor(s, 16);
                    s += __shfl_xor(s, 32);
                    if (lh == 0) scratch[wv][ntk * 16 + ll] = s;
                }
            }
        }
        __syncthreads();

        // ---- masked softmax over neighbors (wave 0) ----
        if (tid < KN) {
            float s = scratch[0][tid] + scratch[1][tid] + scratch[2][tid] + scratch[3][tid];
            float sv = (tid < len) ? s : -INFINITY;
            float mx = sv;
            #pragma unroll
            for (int off = 1; off < 64; off <<= 1) mx = fmaxf(mx, __shfl_xor(mx, off));
            float e = (tid < len) ? __expf(sv - mx) : 0.f;
            float sum = e;
            #pragma unroll
            for (int off = 1; off < 64; off <<= 1) sum += __shfl_xor(sum, off);
            att_lds[tid] = e / sum;
        }
        __syncthreads();

        // ---- aggregate: agg[j] = sum_{k<len} att[k] * N[k][j]  (b64 reads + shfl fold) ----
        {
            int jg = tid & 31, ks = tid >> 5;   // per wave: ks in {2w, 2w+1}
            int j0 = jg * 4;
            float ax = 0.f, ay = 0.f, az = 0.f, aw = 0.f;
            int kb = ks * 8, ke = min(len, kb + 8);
            for (int k = kb; k < ke; ++k) {
                float av = att_lds[k];
                bf16x4 nv = *(const bf16x4*)&n_lds[k][j0];
                ax = fmaf(av, (float)nv[0], ax);
                ay = fmaf(av, (float)nv[1], ay);
                az = fmaf(av, (float)nv[2], az);
                aw = fmaf(av, (float)nv[3], aw);
            }
            ax += __shfl_xor(ax, 32);
            ay += __shfl_xor(ay, 32);
            az += __shfl_xor(az, 32);
            aw += __shfl_xor(aw, 32);
            if ((tid & 63) < 32) {
                float4 v4 = {ax, ay, az, aw};
                *(float4*)&scratch[wv][j0] = v4;
            }
        }
        __syncthreads();
        if (tid < DIM)
            out[((size_t)(2 + m) * NB + b) * DIM + tid] =
                scratch[0][tid] + scratch[1][tid] + scratch[2][tid] + scratch[3][tid];
        __syncthreads();  // protect n_lds/scratch before next modality
    }
}

extern "C" void kernel_launch(void* const* d_in, const int* in_sizes, int n_in,
                              void* d_out, int out_size, void* d_ws, size_t ws_size,
                              hipStream_t stream) {
    const int*   node_idx  = (const int*)d_in[0];
    const int*   neigh_idx = (const int*)d_in[1];
    const int*   neigh_len = (const int*)d_in[2];
    const float* emb_v     = (const float*)d_in[3];
    const float* emb_t     = (const float*)d_in[4];
    const float* w1        = (const float*)d_in[5];
    const float* b1        = (const float*)d_in[6];
    const float* w2        = (const float*)d_in[7];
    const float* b2        = (const float*)d_in[8];
    const float* w3        = (const float*)d_in[9];
    float* out = (float*)d_out;

    bf16* w1T = (bf16*)d_ws;                 // 128*256 bf16 = 64 KiB
    bf16* w2T = (bf16*)d_ws + 128 * 256;     // 128*128 bf16 = 32 KiB

    hipLaunchKernelGGL(prep_weights, dim3(192), dim3(256), 0, stream, w1, w2, w1T, w2T);
    hipLaunchKernelGGL(graphsage_mfma, dim3(NB), dim3(256), 0, stream,
                       node_idx, neigh_idx, neigh_len, emb_v, emb_t,
                       w1T, b1, w2T, b2, w3, out);
}